// Round 8
// baseline (223.345 us; speedup 1.0000x reference)
//
#include <hip/hip_runtime.h>
#include <hip/hip_bf16.h>
#include <math.h>

#define B_ 64
#define L_ 512
#define D_ 768
#define H_ 384
#define T_ 9
#define M_ (B_ * L_)   // 32768 rows

typedef __attribute__((ext_vector_type(8))) short short8;
typedef __attribute__((ext_vector_type(4))) float f32x4;

__device__ __forceinline__ unsigned short f2bf(float f) {
    unsigned u = __float_as_uint(f);
    u += 0x7FFFu + ((u >> 16) & 1u);   // RNE
    return (unsigned short)(u >> 16);
}

// packed f32x2 -> bf16x2 (v_cvt_pk_bf16_f32 on gfx950)
__device__ __forceinline__ unsigned pkbf2(float a, float b) {
    __hip_bfloat162 h = __float22bfloat162_rn(float2{a, b});
    return *(unsigned*)&h;
}

// tanh-form gelu as x * sigmoid(2*0.79788456*(x + 0.044715 x^3)) — 1 exp.
__device__ __forceinline__ float gelu_fast(float x) {
    float z2 = 1.5957691216f * x + 0.0713548162726f * x * x * x;
    return x / (1.f + __expf(-z2));
}

__device__ __forceinline__ float wredf(float v) {
#pragma unroll
    for (int m = 32; m >= 1; m >>= 1) v += __shfl_xor(v, m, 64);
    return v;
}

// LDS-only barrier: global loads stay in flight across it (no vmcnt drain).
__device__ __forceinline__ void sync_lds() {
    asm volatile("s_waitcnt lgkmcnt(0)\n\ts_barrier" ::: "memory");
}

// -----------------------------------------------------------------------------
// Kernel 0: fragment-ordered bf16 weights + zero d_out.
//   W1F[((nt*24 + kc)*64 + lane)*8 + j] = W1[kc*32 + q*8 + j][nt*16 + lm]
//   W2F[(kk*64 + lane)*8 + j]           = (lm<9) ? W2[kk*32 + q*8 + j][lm] : 0
// -----------------------------------------------------------------------------
__global__ __launch_bounds__(256) void prep_kernel(
    const float* __restrict__ W1, const float* __restrict__ W2,
    unsigned short* __restrict__ W1F, unsigned short* __restrict__ W2F,
    float* __restrict__ out)
{
    if (blockIdx.x == 0 && threadIdx.x == 0) out[0] = 0.f;
    const int g    = blockIdx.x * 4 + (threadIdx.x >> 6);
    const int lane = threadIdx.x & 63;
    const int lm   = lane & 15;
    const int q    = lane >> 4;
    if (g < 576) {                       // W1F: g = nt*24 + kc
        const int nt = g / 24;
        const int kc = g - nt * 24;
        const int n  = nt * 16 + lm;
        short8 v;
#pragma unroll
        for (int j = 0; j < 8; ++j)
            v[j] = (short)f2bf(W1[(size_t)(kc * 32 + q * 8 + j) * H_ + n]);
        *(short8*)(W1F + ((size_t)g * 64 + lane) * 8) = v;
    } else if (g < 588) {                // W2F: kk = g - 576
        const int kk = g - 576;
        short8 v;
#pragma unroll
        for (int j = 0; j < 8; ++j) {
            int k = kk * 32 + q * 8 + j;
            v[j] = (lm < 9) ? (short)f2bf(W2[(size_t)k * T_ + lm]) : (short)0;
        }
        *(short8*)(W2F + ((size_t)kk * 64 + lane) * 8) = v;
    }
}

// -----------------------------------------------------------------------------
// Kernel 1: emissions. Grid 512, block 512 thr / 8 waves, launch_bounds(512,4)
// -> <=128 VGPR, 4 waves/SIMD, 16 waves/CU (2 blocks/CU; LDS 2x50 KB).
// r7 bug fixed: wave w owns ALL 4 m-tiles x n-tiles {w*3..w*3+2}
// (8 waves x 12 tiles = 96 = full 64x384 block; r7's (mh,nq) split covered
// only n-tiles 0..11 -> NaN).  acc[4][3] = 48 VGPR, 12 MFMA/wave/k-step.
// Staging (per thread 16 B fp32 -> 8 B bf16): row t>>3, slot8 t&7; swizzled
// chunk (slot8>>1)^((srow>>1)&3), ds_write_b64. Read: 1 ds_read_b128 per
// m-tile at swizzled chunk q^((lm>>1)&3) (verified r5/r6 layout; row
// R=mt*16+lm keeps (R>>1)&3 == (lm>>1)&3).
// Pipeline: X 3 named G sets (issue KC+3, write KC+1 -> 2-step slack);
// W1F 3 named bb sets (2 ahead). ONE lgkm-only barrier per k-step; vmcnt
// never drained at a barrier. All register indices literal (rule #20).
// Epilogue: gelu -> Hs[64][392] -> waves 0-3: 12 MFMA vs W2F -> em (+b2).
// -----------------------------------------------------------------------------
__global__ __launch_bounds__(512, 4) void emis_mfma_kernel(
    const float* __restrict__ X,             // [M_][768] fp32
    const unsigned short* __restrict__ W1F,
    const float* __restrict__ b1,
    const unsigned short* __restrict__ W2F,
    const float* __restrict__ b2,
    float* __restrict__ em)                  // [M_][9] full emissions (+b2)
{
    __shared__ __align__(16) unsigned short Hs[64 * 392];  // 50176 B
    char* smem = (char*)Hs;                  // As[2][4096 B] aliases the head

    const int t    = threadIdx.x;
    const int lane = t & 63;
    const int w    = t >> 6;                 // 0..7
    const int lm   = lane & 15;
    const int q    = lane >> 4;
    const int row0 = blockIdx.x * 64;

    // staging: thread t -> row t>>3, 4-float slot t&7 (16 B fp32 -> 8 B bf16)
    const int srow   = t >> 3;
    const int slot8  = t & 7;
    const int schunk = (slot8 >> 1) ^ ((srow >> 1) & 3);
    const float* sp  = X + (size_t)(row0 + srow) * D_ + slot8 * 4;
    char* swr = smem + srow * 64 + schunk * 16 + (slot8 & 1) * 8;  // + buf*4096

    // fragment read: row R = mt*16 + lm  ->  (R>>1)&3 == (lm>>1)&3
    const int cq = (q ^ ((lm >> 1) & 3)) << 4;       // swizzled 16B chunk byte

    // W1F base: wave w covers n-tiles w*3 .. w*3+2
    const unsigned short* wb = W1F + (size_t)(w * 3) * 12288 + lane * 8;

    f32x4 acc[4][3];
#pragma unroll
    for (int mt = 0; mt < 4; ++mt)
#pragma unroll
        for (int i = 0; i < 3; ++i) acc[mt][i] = (f32x4)0.f;

    short8 bb0[3], bb1[3], bb2[3];       // 3 rotating B-frag sets (2 ahead)
    f32x4 g0, g1, g2;                    // 3 rotating X sets (2-step slack)

#define LOADBB(dst, KC)                                                     \
    do {                                                                    \
        dst[0] = *(const short8*)(wb + 0 * 12288 + (KC) * 512);             \
        dst[1] = *(const short8*)(wb + 1 * 12288 + (KC) * 512);             \
        dst[2] = *(const short8*)(wb + 2 * 12288 + (KC) * 512);             \
    } while (0)

#define STWR(G, BUF)                                                        \
    do {                                                                    \
        int2 v2 = {(int)pkbf2(G[0], G[1]), (int)pkbf2(G[2], G[3])};         \
        *(int2*)(swr + (BUF) * 4096) = v2;                                  \
    } while (0)

    // ---- prologue: tile0 -> LDS buf0; tiles 1,2 in regs; BB(0), BB(1) ----
    g0 = *(const f32x4*)(sp);
    STWR(g0, 0);
    g1 = *(const f32x4*)(sp + 32);
    g2 = *(const f32x4*)(sp + 64);
    LOADBB(bb0, 0);
    LOADBB(bb1, 1);
    sync_lds();

    // KSTEP(KC): issue G(KC+3)->Gn(=g[KC%3]), BB(KC+2)->BBn(=bb[(KC+2)%3]);
    // 4 ds_read + 12 MFMA from buf[KC&1] with BBc(=bb[KC%3]); cvt+write
    // Gw(=g[(KC+1)%3], tile KC+1) -> buf[(KC+1)&1]; one lgkm barrier.
#define KSTEP(KC, BBc, BBn, Gn, Gw)                                         \
    do {                                                                    \
        if ((KC) + 3 <= 23) Gn = *(const f32x4*)(sp + ((KC) + 3) * 32);     \
        if ((KC) + 2 <= 23) { LOADBB(BBn, (KC) + 2); }                      \
        {                                                                   \
            const char* fb = smem + ((KC) & 1) * 4096;                      \
            short8 af0 = *(const short8*)(fb + ( 0 + lm) * 64 + cq);        \
            short8 af1 = *(const short8*)(fb + (16 + lm) * 64 + cq);        \
            short8 af2 = *(const short8*)(fb + (32 + lm) * 64 + cq);        \
            short8 af3 = *(const short8*)(fb + (48 + lm) * 64 + cq);        \
            acc[0][0] = __builtin_amdgcn_mfma_f32_16x16x32_bf16(af0, BBc[0], acc[0][0], 0, 0, 0); \
            acc[0][1] = __builtin_amdgcn_mfma_f32_16x16x32_bf16(af0, BBc[1], acc[0][1], 0, 0, 0); \
            acc[0][2] = __builtin_amdgcn_mfma_f32_16x16x32_bf16(af0, BBc[2], acc[0][2], 0, 0, 0); \
            acc[1][0] = __builtin_amdgcn_mfma_f32_16x16x32_bf16(af1, BBc[0], acc[1][0], 0, 0, 0); \
            acc[1][1] = __builtin_amdgcn_mfma_f32_16x16x32_bf16(af1, BBc[1], acc[1][1], 0, 0, 0); \
            acc[1][2] = __builtin_amdgcn_mfma_f32_16x16x32_bf16(af1, BBc[2], acc[1][2], 0, 0, 0); \
            acc[2][0] = __builtin_amdgcn_mfma_f32_16x16x32_bf16(af2, BBc[0], acc[2][0], 0, 0, 0); \
            acc[2][1] = __builtin_amdgcn_mfma_f32_16x16x32_bf16(af2, BBc[1], acc[2][1], 0, 0, 0); \
            acc[2][2] = __builtin_amdgcn_mfma_f32_16x16x32_bf16(af2, BBc[2], acc[2][2], 0, 0, 0); \
            acc[3][0] = __builtin_amdgcn_mfma_f32_16x16x32_bf16(af3, BBc[0], acc[3][0], 0, 0, 0); \
            acc[3][1] = __builtin_amdgcn_mfma_f32_16x16x32_bf16(af3, BBc[1], acc[3][1], 0, 0, 0); \
            acc[3][2] = __builtin_amdgcn_mfma_f32_16x16x32_bf16(af3, BBc[2], acc[3][2], 0, 0, 0); \
        }                                                                   \
        if ((KC) + 1 <= 23) {                                               \
            STWR(Gw, ((KC) + 1) & 1);                                       \
            sync_lds();                                                     \
        }                                                                   \
    } while (0)

    //      KC   BBc  BBn  Gn  Gw
    KSTEP(  0,  bb0, bb2, g0, g1);
    KSTEP(  1,  bb1, bb0, g1, g2);
    KSTEP(  2,  bb2, bb1, g2, g0);
    KSTEP(  3,  bb0, bb2, g0, g1);
    KSTEP(  4,  bb1, bb0, g1, g2);
    KSTEP(  5,  bb2, bb1, g2, g0);
    KSTEP(  6,  bb0, bb2, g0, g1);
    KSTEP(  7,  bb1, bb0, g1, g2);
    KSTEP(  8,  bb2, bb1, g2, g0);
    KSTEP(  9,  bb0, bb2, g0, g1);
    KSTEP( 10,  bb1, bb0, g1, g2);
    KSTEP( 11,  bb2, bb1, g2, g0);
    KSTEP( 12,  bb0, bb2, g0, g1);
    KSTEP( 13,  bb1, bb0, g1, g2);
    KSTEP( 14,  bb2, bb1, g2, g0);
    KSTEP( 15,  bb0, bb2, g0, g1);
    KSTEP( 16,  bb1, bb0, g1, g2);
    KSTEP( 17,  bb2, bb1, g2, g0);
    KSTEP( 18,  bb0, bb2, g0, g1);
    KSTEP( 19,  bb1, bb0, g1, g2);
    KSTEP( 20,  bb2, bb1, g2, g0);
    KSTEP( 21,  bb0, bb2, g0, g1);
    KSTEP( 22,  bb1, bb0, g1, g2);
    KSTEP( 23,  bb2, bb1, g2, g0);

#undef KSTEP
#undef LOADBB
#undef STWR

    __syncthreads();   // all ds_reads done before Hs (alias) is written

    // ---- epilogue A: +b1, gelu -> Hs[64][392] (wave w: cols w*48..w*48+47) --
#pragma unroll
    for (int i = 0; i < 3; ++i) {
        const int lc = w * 48 + i * 16 + lm;
        const float b1v = b1[lc];
#pragma unroll
        for (int mt = 0; mt < 4; ++mt)
#pragma unroll
            for (int r = 0; r < 4; ++r) {
                float h = gelu_fast(acc[mt][i][r] + b1v);
                Hs[(mt * 16 + q * 4 + r) * 392 + lc] = f2bf(h);
            }
    }
    __syncthreads();

    // ---- epilogue B: em = h @ W2 via 12 MFMA (waves 0..3, m-tile w) ----
    if (w < 4) {
        f32x4 e = (f32x4)0.f;
#pragma unroll
        for (int kk = 0; kk < 12; ++kk) {
            short8 ah = *(const short8*)&Hs[(w * 16 + lm) * 392 + kk * 32 + (q << 3)];
            short8 bw = *(const short8*)(W2F + ((size_t)(kk * 64 + lane)) * 8);
            e = __builtin_amdgcn_mfma_f32_16x16x32_bf16(ah, bw, e, 0, 0, 0);
        }
        if (lm < 9) {
#pragma unroll
            for (int r = 0; r < 4; ++r)
                em[(size_t)(row0 + w * 16 + q * 4 + r) * T_ + lm] = e[r] + b2[lm];
        }
    }
}

// -----------------------------------------------------------------------------
// Kernel 2: CRF. 64 blocks x 640 threads. (Single em input.)
// Phase A: threads 0..575 = (chunk c, row i0) build 9x9 transfer matrices;
// wave 9 computes the numerator concurrently. Phase B: 6-level tree combine.
// Final: alpha0 x M_total, logsumexp, atomicAdd (denom-numer)/B.
// -----------------------------------------------------------------------------
__global__ __launch_bounds__(640) void crf_kernel(
    const float* __restrict__ em,
    const int* __restrict__ labels,
    const unsigned char* __restrict__ maskb,
    const float* __restrict__ st,
    const float* __restrict__ et,
    const float* __restrict__ tr,
    float* __restrict__ out)
{
    const int b = blockIdx.x;
    const int t = threadIdx.x;

    __shared__ float es[64 * 73];    // es[c*73 + s*9 + j]
    __shared__ float Msa[64 * 81];
    __shared__ float Msb[32 * 81];
    __shared__ float trs[81];
    __shared__ float red_num;
    __shared__ unsigned char msh[L_];
    __shared__ int lbs[L_];

    const int mstride =
        (maskb[0] != 0 && maskb[1] == 0 && maskb[2] == 0 && maskb[3] == 0) ? 4 : 1;

    const float* e0 = em + (size_t)b * L_ * T_;
    for (int i = t; i < L_ * T_; i += 640) {
        int tt = i / T_, j = i - tt * T_;
        es[(tt >> 3) * 73 + (tt & 7) * 9 + j] = e0[i];
    }
    if (t < 81) trs[t] = tr[t];
    for (int i = t; i < L_; i += 640) {
        msh[i] = maskb[((size_t)b * L_ + i) * (size_t)mstride];
        lbs[i] = labels[b * L_ + i];
    }
    __syncthreads();

    if (t < 576) {
        // ---- Phase A ----
        const int c  = t / 9;
        const int i0 = t - c * 9;
        float trr[81];
#pragma unroll
        for (int i = 0; i < 81; ++i) trr[i] = trs[i];
        float V[9];
#pragma unroll
        for (int j = 0; j < 9; ++j) V[j] = (j == i0) ? 0.f : -1e30f;

        const int sbeg = (c == 0) ? 1 : 0;
        for (int s = sbeg; s < 8; ++s) {
            int tt = c * 8 + s;
            if (msh[tt]) {
                const float* ep = &es[c * 73 + s * 9];
                float nv[9];
#pragma unroll
                for (int j = 0; j < 9; ++j) {
                    float a[9];
#pragma unroll
                    for (int k = 0; k < 9; ++k) a[k] = V[k] + trr[k * 9 + j];
                    float mx = a[0];
#pragma unroll
                    for (int k = 1; k < 9; ++k) mx = fmaxf(mx, a[k]);
                    float sum = 0.f;
#pragma unroll
                    for (int k = 0; k < 9; ++k) sum += __expf(a[k] - mx);
                    nv[j] = ep[j] + mx + __logf(sum);
                }
#pragma unroll
                for (int j = 0; j < 9; ++j) V[j] = nv[j];
            }
        }
#pragma unroll
        for (int j = 0; j < 9; ++j) Msa[c * 81 + i0 * 9 + j] = V[j];
    } else {
        // ---- numerator (wave 9, concurrent with Phase A) ----
        const int lane = t - 576;
        float emit_s = 0.f, tr_sc = 0.f, mcnt = 0.f;
        for (int tt = lane; tt < L_; tt += 64) {
            if (msh[tt]) {
                mcnt += 1.f;
                int tag = lbs[tt];
                emit_s += es[(tt >> 3) * 73 + (tt & 7) * 9 + tag];
                if (tt >= 1) tr_sc += trs[lbs[tt - 1] * 9 + tag];
            }
        }
        emit_s = wredf(emit_s);
        tr_sc  = wredf(tr_sc);
        mcnt   = wredf(mcnt);
        if (lane == 0) {
            int last = (int)mcnt - 1;
            red_num = st[lbs[0]] + emit_s + tr_sc + et[lbs[last]];
        }
    }
    __syncthreads();

    // ---- Phase B: tree combine, 6 levels ----
    float* src = Msa;
    float* dst = Msb;
    for (int n = 32; n >= 1; n >>= 1) {
        for (int idx = t; idx < n * 81; idx += 640) {
            int p = idx / 81;
            int r = idx - p * 81;
            int i = r / 9, j = r - i * 9;
            const float* A  = src + (2 * p) * 81 + i * 9;
            const float* Bm = src + (2 * p + 1) * 81 + j;
            float v[9];
#pragma unroll
            for (int k = 0; k < 9; ++k) v[k] = A[k] + Bm[k * 9];
            float mx = v[0];
#pragma unroll
            for (int k = 1; k < 9; ++k) mx = fmaxf(mx, v[k]);
            float sum = 0.f;
#pragma unroll
            for (int k = 0; k < 9; ++k) sum += __expf(v[k] - mx);
            dst[p * 81 + r] = mx + __logf(sum);
        }
        __syncthreads();
        float* tmp = src; src = dst; dst = tmp;
    }
    // final matrix in src (= Msa after 6 swaps)

    if (t < 64) {
        float v = -3.0e38f;
        if (t < 9) {
            float a[9];
#pragma unroll
            for (int i = 0; i < 9; ++i) a[i] = st[i] + es[i] + src[i * 9 + t];
            float mx = a[0];
#pragma unroll
            for (int i = 1; i < 9; ++i) mx = fmaxf(mx, a[i]);
            float sum = 0.f;
#pragma unroll
            for (int i = 0; i < 9; ++i) sum += __expf(a[i] - mx);
            v = mx + __logf(sum) + et[t];
        }
        float mx = v;
#pragma unroll
        for (int m = 32; m >= 1; m >>= 1) mx = fmaxf(mx, __shfl_xor(mx, m, 64));
        float sm = __expf(v - mx);
        sm = wredf(sm);
        if (t == 0) {
            float denom = mx + __logf(sm);
            atomicAdd(out, (denom - red_num) * (1.0f / (float)B_));
        }
    }
}

extern "C" void kernel_launch(void* const* d_in, const int* in_sizes, int n_in,
                              void* d_out, int out_size, void* d_ws, size_t ws_size,
                              hipStream_t stream) {
    const float*         enc    = (const float*)d_in[0];
    const int*           labels = (const int*)d_in[1];
    const unsigned char* mask   = (const unsigned char*)d_in[2];
    const float*         W1     = (const float*)d_in[3];
    const float*         b1     = (const float*)d_in[4];
    const float*         W2     = (const float*)d_in[5];
    const float*         b2     = (const float*)d_in[6];
    const float*         st     = (const float*)d_in[7];
    const float*         et     = (const float*)d_in[8];
    const float*         tr     = (const float*)d_in[9];

    float* em           = (float*)d_ws;                        // 1,179,648 B
    unsigned short* W1F = (unsigned short*)(em + (size_t)M_ * T_);   // 589,824 B
    unsigned short* W2F = W1F + (size_t)576 * 64 * 8;          // 12,288 B

    prep_kernel<<<147, 256, 0, stream>>>(W1, W2, W1F, W2F, (float*)d_out);
    emis_mfma_kernel<<<512, 512, 0, stream>>>(enc, W1F, b1, W2F, b2, em);
    crf_kernel<<<B_, 640, 0, stream>>>(em, labels, mask, st, et, tr, (float*)d_out);
}